// Round 1
// baseline (26832.101 us; speedup 1.0000x reference)
//
#include <hip/hip_runtime.h>
#include <math.h>

#define Bsz 32
#define Lsz 2048
#define Ssz 32
#define Csz 64
#define Tsz 17
#define Hsz 32
#define NT  512

// ---------------- LDS layout (floats) ----------------
#define O_Wx1   0           // 18*128 = 2304
#define O_Wh1   2304        // 32*128 = 4096
#define O_Wx2   6400        // 4096
#define O_Wh2   10496       // 4096
#define O_Wd1   14592       // 31*64 = 1984
#define O_Wd2   16576       // 64*64 = 4096
#define O_Wf    20672       // 32*32 = 1024 (= Wo@Wlin)
#define O_Mu    21696       // 17*33 padded = 561 -> 564
#define O_B1    22260       // 128
#define O_B2    22388       // 128
#define O_Bd1   22516       // 64
#define O_Bd2   22580       // 64
#define O_Bf    22644       // 32  (= bo@Wlin + blin)
#define O_Ns    22676       // 64*32 = 2048
#define O_State 24724       // 32
#define O_H1    24756       // 32
#define O_C1    24788       // 32
#define O_H2    24820       // 32
#define O_C2    24852       // 32
#define O_Gate  24884       // 64
#define O_Inp   24948       // 20 (18 used)
#define O_Z1    24968       // 128
#define O_Z2    25096       // 128
#define O_Co    25224       // 32
#define O_D1    25256       // 64
#define O_XY    25320       // 4  (x[t&1], y[t&1] double buffer)
#define O_Err   25324       // 4
#define SMEM_FLOATS 25328

__device__ __forceinline__ float sigf(float v) {
    return 1.0f / (1.0f + __expf(-v));
}
__device__ __forceinline__ float ftanh(float v) {
    // tanh(x) = 1 - 2/(e^{2x}+1); saturates correctly at +-inf
    float e = __expf(2.0f * v);
    return 1.0f - 2.0f / (e + 1.0f);
}

extern "C" __global__ __launch_bounds__(NT)
void dnc_kernel(const float* __restrict__ x,   const float* __restrict__ y,
                const float* __restrict__ s0,  const float* __restrict__ err0,
                const float* __restrict__ gate0,
                const float* __restrict__ Wc,  const float* __restrict__ Ux,
                const float* __restrict__ bc,  const float* __restrict__ mu,
                const float* __restrict__ Wx1, const float* __restrict__ Wh1,
                const float* __restrict__ b1,
                const float* __restrict__ Wx2, const float* __restrict__ Wh2,
                const float* __restrict__ b2,
                const float* __restrict__ Wo,  const float* __restrict__ bo,
                const float* __restrict__ Wlin,const float* __restrict__ blin,
                const float* __restrict__ Wd1, const float* __restrict__ bd1,
                const float* __restrict__ Wd2, const float* __restrict__ bd2,
                float* __restrict__ out)
{
    extern __shared__ float sm[];
    const int tid = threadIdx.x;
    const int b   = blockIdx.x;

    // ---------------- prologue: stage weights into LDS ----------------
    for (int i = tid; i < 18 * 128; i += NT) sm[O_Wx1 + i] = Wx1[i];
    for (int i = tid; i < 32 * 128; i += NT) sm[O_Wh1 + i] = Wh1[i];
    for (int i = tid; i < 32 * 128; i += NT) sm[O_Wx2 + i] = Wx2[i];
    for (int i = tid; i < 32 * 128; i += NT) sm[O_Wh2 + i] = Wh2[i];
    for (int i = tid; i < 31 * 64;  i += NT) sm[O_Wd1 + i] = Wd1[i];
    for (int i = tid; i < 64 * 64;  i += NT) sm[O_Wd2 + i] = Wd2[i];
    for (int i = tid; i < 17 * 32;  i += NT) sm[O_Mu + (i >> 5) * 33 + (i & 31)] = mu[i];
    if (tid < 128) { sm[O_B1 + tid] = b1[tid]; sm[O_B2 + tid] = b2[tid]; }
    if (tid < 64)  { sm[O_Bd1 + tid] = bd1[tid]; sm[O_Bd2 + tid] = bd2[tid]; }
    // Wf = Wo @ Wlin  (32x18 @ 18x32), bf = bo @ Wlin + blin
    for (int i = tid; i < 1024; i += NT) {
        int k = i >> 5, j = i & 31;
        float a = 0.0f;
        for (int m = 0; m < 18; ++m) a += Wo[k * 18 + m] * Wlin[m * 32 + j];
        sm[O_Wf + i] = a;
    }
    if (tid < 32) {
        float a = blin[tid];
        for (int m = 0; m < 18; ++m) a += bo[m] * Wlin[m * 32 + tid];
        sm[O_Bf + tid] = a;
    }
    // recurrent state init
    if (tid < 32) {
        sm[O_State + tid] = s0[tid];
        sm[O_H1 + tid] = 0.0f; sm[O_C1 + tid] = 0.0f;
        sm[O_H2 + tid] = 0.0f; sm[O_C2 + tid] = 0.0f;
    }
    if (tid < 64) sm[O_Gate + tid] = gate0[b * 64 + tid];
    if (tid == 0) {
        sm[O_Err]    = err0[b];
        sm[O_XY + 0] = x[b * Lsz + 0];
        sm[O_XY + 1] = y[b * Lsz + 0];
    }

    // ---------------- per-thread register-resident Wc slice ----------------
    // thread owns outputs o = tid*4 .. tid*4+3  ->  c = tid>>3, d0 = (tid&7)*4
    const int c  = tid >> 3;
    const int d0 = (tid & 7) * 4;
    float4 wc[32];
    #pragma unroll
    for (int s = 0; s < 32; ++s)
        wc[s] = *(const float4*)(&Wc[(c * 32 + s) * 32 + d0]);
    const float4 uxv = *(const float4*)(&Ux[c * 32 + d0]);
    const float4 bcv = *(const float4*)(&bc[c * 32 + d0]);

    __syncthreads();

    // ---------------- time loop ----------------
    for (int t = 0; t < Lsz; ++t) {
        const int par = t & 1;

        // ---- P1: einsum (all threads) + enc (threads 0..16) ----
        const float xt = sm[O_XY + par * 2 + 0];
        float4 st4[8];
        #pragma unroll
        for (int q = 0; q < 8; ++q)
            st4[q] = *(const float4*)(&sm[O_State + q * 4]);
        const float* stf = (const float*)st4;

        float ax = bcv.x + xt * uxv.x;
        float ay = bcv.y + xt * uxv.y;
        float az = bcv.z + xt * uxv.z;
        float aw = bcv.w + xt * uxv.w;
        #pragma unroll
        for (int s = 0; s < 32; ++s) {
            const float sv = stf[s];
            ax += sv * wc[s].x;
            ay += sv * wc[s].y;
            az += sv * wc[s].z;
            aw += sv * wc[s].w;
        }
        float4 nsv;
        nsv.x = ftanh(ax); nsv.y = ftanh(ay); nsv.z = ftanh(az); nsv.w = ftanh(aw);
        *(float4*)(&sm[O_Ns + tid * 4]) = nsv;

        if (tid < Tsz) {
            float acc = 0.0f;
            #pragma unroll
            for (int s = 0; s < 32; ++s) {
                float d = stf[s] - sm[O_Mu + tid * 33 + s];
                acc += d * d;
            }
            sm[O_Inp + tid] = __expf(-0.5f * acc);
        }
        if (tid == Tsz) sm[O_Inp + Tsz] = sm[O_Err];
        __syncthreads();

        // ---- P2: LSTM1 pre-activations (threads 0..127); x/y prefetch ----
        if (tid < 128) {
            float a = sm[O_B1 + tid];
            for (int k = 0; k < 18; ++k) a += sm[O_Inp + k] * sm[O_Wx1 + k * 128 + tid];
            for (int k = 0; k < 32; ++k) a += sm[O_H1 + k]  * sm[O_Wh1 + k * 128 + tid];
            sm[O_Z1 + tid] = a;
        } else if (tid == 128) {
            if (t + 1 < Lsz) sm[O_XY + (par ^ 1) * 2 + 0] = x[b * Lsz + t + 1];
        } else if (tid == 129) {
            if (t + 1 < Lsz) sm[O_XY + (par ^ 1) * 2 + 1] = y[b * Lsz + t + 1];
        }
        __syncthreads();

        // ---- P3: LSTM1 combine (threads 0..31) ----
        if (tid < 32) {
            float i_ = sm[O_Z1 + tid];
            float f_ = sm[O_Z1 + tid + 32];
            float g_ = sm[O_Z1 + tid + 64];
            float o_ = sm[O_Z1 + tid + 96];
            float cc = sigf(f_) * sm[O_C1 + tid] + sigf(i_) * ftanh(g_);
            float hh = sigf(o_) * ftanh(cc);
            sm[O_C1 + tid] = cc;
            sm[O_H1 + tid] = hh;
        }
        __syncthreads();

        // ---- P4: LSTM2 pre-activations (threads 0..127) ----
        if (tid < 128) {
            float a = sm[O_B2 + tid];
            for (int k = 0; k < 32; ++k) a += sm[O_H1 + k] * sm[O_Wx2 + k * 128 + tid];
            for (int k = 0; k < 32; ++k) a += sm[O_H2 + k] * sm[O_Wh2 + k * 128 + tid];
            sm[O_Z2 + tid] = a;
        }
        __syncthreads();

        // ---- P5: LSTM2 combine + co (threads 0..31, wave 0, shfl) ----
        if (tid < 32) {
            float i_ = sm[O_Z2 + tid];
            float f_ = sm[O_Z2 + tid + 32];
            float g_ = sm[O_Z2 + tid + 64];
            float o_ = sm[O_Z2 + tid + 96];
            float cc = sigf(f_) * sm[O_C2 + tid] + sigf(i_) * ftanh(g_);
            float hh = sigf(o_) * ftanh(cc);
            sm[O_C2 + tid] = cc;
            sm[O_H2 + tid] = hh;
            float a = sm[O_Bf + tid];
            #pragma unroll
            for (int k = 0; k < 32; ++k)
                a += __shfl(hh, k) * sm[O_Wf + k * 32 + tid];
            sm[O_Co + tid] = a;
        }
        __syncthreads();

        // ---- P6: d1 = relu(co[:31] @ Wd1 + bd1) (threads 0..63) ----
        if (tid < 64) {
            float a = sm[O_Bd1 + tid];
            for (int k = 0; k < 31; ++k) a += sm[O_Co + k] * sm[O_Wd1 + k * 64 + tid];
            sm[O_D1 + tid] = fmaxf(a, 0.0f);
        }
        __syncthreads();

        // ---- P7: logits + softmax + gate (threads 0..63 = wave 0) ----
        if (tid < 64) {
            float a = sm[O_Bd2 + tid];
            for (int k = 0; k < 64; ++k) a += sm[O_D1 + k] * sm[O_Wd2 + k * 64 + tid];
            float mx = a;
            #pragma unroll
            for (int o = 32; o >= 1; o >>= 1) mx = fmaxf(mx, __shfl_xor(mx, o));
            float e = __expf(a - mx);
            float ssum = e;
            #pragma unroll
            for (int o = 32; o >= 1; o >>= 1) ssum += __shfl_xor(ssum, o);
            float g = e / ssum;
            float theta = sigf(sm[O_Co + 31]);
            sm[O_Gate + tid] = g * theta + sm[O_Gate + tid] * (1.0f - theta);
        }
        __syncthreads();

        // ---- P8: state update + pred + error (threads 0..31) ----
        if (tid < 32) {
            float a = 0.0f;
            for (int k = 0; k < 64; ++k) a += sm[O_Gate + k] * sm[O_Ns + k * 32 + tid];
            sm[O_State + tid] = a;
            if (tid == 31) {
                float p = fminf(fmaxf(a, 0.0f), 1.0f);
                out[b * Lsz + t] = p;
                sm[O_Err] = p - sm[O_XY + par * 2 + 1];
            }
        }
        __syncthreads();
    }
}

extern "C" void kernel_launch(void* const* d_in, const int* in_sizes, int n_in,
                              void* d_out, int out_size, void* d_ws, size_t ws_size,
                              hipStream_t stream) {
    const float* x    = (const float*)d_in[0];
    const float* y    = (const float*)d_in[1];
    const float* s0   = (const float*)d_in[2];
    const float* err0 = (const float*)d_in[3];
    const float* g0   = (const float*)d_in[4];
    const float* Wc   = (const float*)d_in[5];
    const float* Ux   = (const float*)d_in[6];
    const float* bc   = (const float*)d_in[7];
    const float* mu   = (const float*)d_in[8];
    const float* Wx1  = (const float*)d_in[9];
    const float* Wh1  = (const float*)d_in[10];
    const float* b1   = (const float*)d_in[11];
    const float* Wx2  = (const float*)d_in[12];
    const float* Wh2  = (const float*)d_in[13];
    const float* b2   = (const float*)d_in[14];
    const float* Wo   = (const float*)d_in[15];
    const float* bo   = (const float*)d_in[16];
    const float* Wlin = (const float*)d_in[17];
    const float* blin = (const float*)d_in[18];
    const float* Wd1  = (const float*)d_in[19];
    const float* bd1  = (const float*)d_in[20];
    const float* Wd2  = (const float*)d_in[21];
    const float* bd2  = (const float*)d_in[22];
    float* out = (float*)d_out;

    static bool attr_set = false;
    if (!attr_set) {
        hipFuncSetAttribute((const void*)dnc_kernel,
                            hipFuncAttributeMaxDynamicSharedMemorySize,
                            SMEM_FLOATS * sizeof(float));
        attr_set = true;
    }

    hipLaunchKernelGGL(dnc_kernel, dim3(Bsz), dim3(NT),
                       SMEM_FLOATS * sizeof(float), stream,
                       x, y, s0, err0, g0, Wc, Ux, bc, mu,
                       Wx1, Wh1, b1, Wx2, Wh2, b2,
                       Wo, bo, Wlin, blin, Wd1, bd1, Wd2, bd2, out);
}

// Round 2
// 13417.078 us; speedup vs baseline: 1.9998x; 1.9998x over previous
//
#include <hip/hip_runtime.h>
#include <math.h>

#define Bsz 32
#define Lsz 2048
#define NT  512

// ---------------- LDS layout (float offsets) ----------------
// Transposed, XOR-swizzled weight copies (row-major per OUTPUT, b128 reads)
#define O_Wx1T  0        // [128][32] = 4096   (cols 18..31 zero)
#define O_Wh1T  4096     // [128][32] = 4096
#define O_Wx2T  8192     // [128][32] = 4096
#define O_Wh2T  12288    // [128][32] = 4096
#define O_Wd1T  16384    // [64][32]  = 2048   (col 31 zero)
#define O_Wd2T  18432    // [64][64]  = 4096
#define O_WfT   22528    // [32][32]  = 1024   (Wf = Wo@Wlin, transposed)
#define O_Mu    23552    // [17][36]  = 612 -> 616
#define O_B1    24168    // 128
#define O_B2    24296    // 128
#define O_Bd1   24424    // 64
#define O_Bd2   24488    // 64
#define O_Bf    24552    // 32  (bo@Wlin + blin)
#define O_NsT   24584    // [32][66] = 2112  (nsT[d][c])
#define O_State 26696    // 32
#define O_H1    26728    // 32
#define O_H2    26760    // 32
#define O_Inp   26792    // 32 (18 used, rest 0)
#define O_Co    26824    // 32
#define O_D1    26856    // 64
#define O_Gate  26920    // 64
#define O_Err   26984    // 4
#define O_X     26988    // 2048
#define O_Y     29036    // 2048
#define O_Pred  31084    // 2048
#define SMEM_FLOATS 33132

// swizzle: row j, element k -> float offset within row
#define SW32(j,k) (((((k) >> 2) ^ ((j) & 7)) << 2) | ((k) & 3))
#define SW64(j,k) (((((k) >> 2) ^ ((j) & 7)) << 2) | ((k) & 3))

__device__ __forceinline__ float sigf(float v) {
    return 1.0f / (1.0f + __expf(-v));
}
__device__ __forceinline__ float ftanh(float v) {
    float e = __expf(2.0f * v);
    return 1.0f - 2.0f / (e + 1.0f);
}
__device__ __forceinline__ float dot4(float4 a, float4 b) {
    return a.x*b.x + a.y*b.y + a.z*b.z + a.w*b.w;
}
// swizzled float4 load: row `row`, block g (floats 4g..4g+3), row width W
__device__ __forceinline__ float4 ldsw(const float* p, int row, int g, int W) {
    return *(const float4*)(p + row * W + (((g ^ (row & 7)) << 2)));
}
// compiler memory/scheduling fence, zero HW cost (intra-wave LDS handoff)
#define WFENCE() do { __builtin_amdgcn_wave_barrier(); } while (0)

extern "C" __global__ __launch_bounds__(NT, 2)
void dnc_kernel(const float* __restrict__ x,   const float* __restrict__ y,
                const float* __restrict__ s0,  const float* __restrict__ err0,
                const float* __restrict__ gate0,
                const float* __restrict__ Wc,  const float* __restrict__ Ux,
                const float* __restrict__ bc,  const float* __restrict__ mu,
                const float* __restrict__ Wx1, const float* __restrict__ Wh1,
                const float* __restrict__ b1,
                const float* __restrict__ Wx2, const float* __restrict__ Wh2,
                const float* __restrict__ b2,
                const float* __restrict__ Wo,  const float* __restrict__ bo,
                const float* __restrict__ Wlin,const float* __restrict__ blin,
                const float* __restrict__ Wd1, const float* __restrict__ bd1,
                const float* __restrict__ Wd2, const float* __restrict__ bd2,
                float* __restrict__ out)
{
    extern __shared__ float sm[];
    const int tid = threadIdx.x;
    const int b   = blockIdx.x;

    // ---------------- prologue: stage transposed/swizzled weights ----------------
    for (int i = tid; i < 4096; i += NT) { int j = i & 127, k = i >> 7;
        sm[O_Wx1T + j*32 + SW32(j,k)] = (k < 18) ? Wx1[k*128 + j] : 0.0f; }
    for (int i = tid; i < 4096; i += NT) { int j = i & 127, k = i >> 7;
        sm[O_Wh1T + j*32 + SW32(j,k)] = Wh1[k*128 + j]; }
    for (int i = tid; i < 4096; i += NT) { int j = i & 127, k = i >> 7;
        sm[O_Wx2T + j*32 + SW32(j,k)] = Wx2[k*128 + j]; }
    for (int i = tid; i < 4096; i += NT) { int j = i & 127, k = i >> 7;
        sm[O_Wh2T + j*32 + SW32(j,k)] = Wh2[k*128 + j]; }
    for (int i = tid; i < 2048; i += NT) { int j = i & 63, k = i >> 6;
        sm[O_Wd1T + j*32 + SW32(j,k)] = (k < 31) ? Wd1[k*64 + j] : 0.0f; }
    for (int i = tid; i < 4096; i += NT) { int j = i & 63, k = i >> 6;
        sm[O_Wd2T + j*64 + SW64(j,k)] = Wd2[k*64 + j]; }
    for (int i = tid; i < 1024; i += NT) { int j = i & 31, k = i >> 5;
        float a = 0.0f;
        for (int m = 0; m < 18; ++m) a += Wo[k*18 + m] * Wlin[m*32 + j];
        sm[O_WfT + j*32 + SW32(j,k)] = a; }
    for (int i = tid; i < 17*32; i += NT) { int r = i >> 5, s2 = i & 31;
        sm[O_Mu + r*36 + s2] = mu[i]; }
    if (tid < 128) { sm[O_B1 + tid] = b1[tid]; sm[O_B2 + tid] = b2[tid]; }
    if (tid < 64)  { sm[O_Bd1 + tid] = bd1[tid]; sm[O_Bd2 + tid] = bd2[tid]; }
    if (tid < 32)  {
        float a = blin[tid];
        for (int m = 0; m < 18; ++m) a += bo[m] * Wlin[m*32 + tid];
        sm[O_Bf + tid] = a;
        sm[O_State + tid] = s0[tid];
        sm[O_H1 + tid] = 0.0f; sm[O_H2 + tid] = 0.0f;
    }
    if (tid >= 18 && tid < 32) sm[O_Inp + tid] = 0.0f;
    if (tid == 0) sm[O_Err] = err0[b];
    for (int i = tid; i < Lsz; i += NT) sm[O_X + i] = x[b*Lsz + i];
    for (int i = tid; i < Lsz; i += NT) sm[O_Y + i] = y[b*Lsz + i];

    // ---------------- per-branch register state ----------------
    // einsum threads (tid>=64): register-resident Wc slice, 5 outputs each
    const int e = tid - 64;
    float wcr[5][32]; float uxr[5], bcr[5];
    // wave-0 lanes: LSTM cell states + gate in registers
    float c1 = 0.0f, c2 = 0.0f, gate_reg = 0.0f;

    if (tid >= 64) {
        #pragma unroll
        for (int k = 0; k < 5; ++k) {
            const int o = e + k*448;
            const bool v = (o < 2048);
            const int c = o >> 5, d = o & 31;
            uxr[k] = v ? Ux[c*32 + d] : 0.0f;
            bcr[k] = v ? bc[c*32 + d] : 0.0f;
            #pragma unroll
            for (int s = 0; s < 32; ++s)
                wcr[k][s] = v ? Wc[c*1024 + s*32 + d] : 0.0f;
        }
    } else {
        gate_reg = gate0[b*64 + tid];
    }

    // ---------------- time loop: 2 barriers/step ----------------
    for (int t = 0; t < Lsz; ++t) {
        __syncthreads();   // A: state/err from prev P8 visible; nsT consumed

        if (tid >= 64) {
            // ======== einsum: ns[c][d] = tanh(state@Wc + x*Ux + bc) ========
            float st[32];
            #pragma unroll
            for (int g = 0; g < 8; ++g)
                *(float4*)&st[g*4] = *(const float4*)&sm[O_State + g*4];
            const float xt = sm[O_X + t];
            #pragma unroll
            for (int k = 0; k < 5; ++k) {
                float acc = bcr[k] + xt * uxr[k];
                #pragma unroll
                for (int s = 0; s < 32; ++s) acc += st[s] * wcr[k][s];
                const int o = e + k*448;
                if (o < 2048)
                    sm[O_NsT + (o & 31)*66 + (o >> 5)] = ftanh(acc);
            }
        } else {
            // ======== wave-0 serial chain (no barriers, intra-wave order) ====
            // -- enc: inp[0..16] = exp(-0.5*||state-mu||^2), inp[17] = err --
            {
                const int mr = (tid < 17) ? tid : 0;
                float acc = 0.0f;
                #pragma unroll
                for (int g = 0; g < 8; ++g) {
                    float4 sv = *(const float4*)&sm[O_State + g*4];
                    float4 m  = *(const float4*)&sm[O_Mu + mr*36 + g*4];
                    float dx = sv.x - m.x, dy = sv.y - m.y,
                          dz = sv.z - m.z, dw = sv.w - m.w;
                    acc += dx*dx + dy*dy + dz*dz + dw*dw;
                }
                if (tid < 17) sm[O_Inp + tid] = __expf(-0.5f * acc);
                if (tid == 17) sm[O_Inp + 17] = sm[O_Err];
            }
            WFENCE();
            // -- z1 = inp@Wx1 + h1@Wh1 + b1 (outputs tid, tid+64) --
            float a0 = sm[O_B1 + tid];
            float a1 = sm[O_B1 + 64 + tid];
            #pragma unroll
            for (int g = 0; g < 8; ++g) {
                float4 xv = *(const float4*)&sm[O_Inp + g*4];
                a0 += dot4(xv, ldsw(sm + O_Wx1T, tid,      g, 32));
                a1 += dot4(xv, ldsw(sm + O_Wx1T, tid + 64, g, 32));
            }
            #pragma unroll
            for (int g = 0; g < 8; ++g) {
                float4 hv = *(const float4*)&sm[O_H1 + g*4];
                a0 += dot4(hv, ldsw(sm + O_Wh1T, tid,      g, 32));
                a1 += dot4(hv, ldsw(sm + O_Wh1T, tid + 64, g, 32));
            }
            // -- LSTM1 combine (i=a0 lanes<32, f=a0 lanes>=32, g=a1, o=a1hi) --
            {
                float zf = __shfl(a0, tid + 32);
                float zo = __shfl(a1, tid + 32);
                if (tid < 32) {
                    c1 = sigf(zf) * c1 + sigf(a0) * ftanh(a1);
                    sm[O_H1 + tid] = sigf(zo) * ftanh(c1);
                }
            }
            WFENCE();
            // -- z2 = h1@Wx2 + h2@Wh2 + b2 --
            a0 = sm[O_B2 + tid];
            a1 = sm[O_B2 + 64 + tid];
            #pragma unroll
            for (int g = 0; g < 8; ++g) {
                float4 hv = *(const float4*)&sm[O_H1 + g*4];
                a0 += dot4(hv, ldsw(sm + O_Wx2T, tid,      g, 32));
                a1 += dot4(hv, ldsw(sm + O_Wx2T, tid + 64, g, 32));
            }
            #pragma unroll
            for (int g = 0; g < 8; ++g) {
                float4 hv = *(const float4*)&sm[O_H2 + g*4];
                a0 += dot4(hv, ldsw(sm + O_Wh2T, tid,      g, 32));
                a1 += dot4(hv, ldsw(sm + O_Wh2T, tid + 64, g, 32));
            }
            // -- LSTM2 combine --
            {
                float zf = __shfl(a0, tid + 32);
                float zo = __shfl(a1, tid + 32);
                if (tid < 32) {
                    c2 = sigf(zf) * c2 + sigf(a0) * ftanh(a1);
                    sm[O_H2 + tid] = sigf(zo) * ftanh(c2);
                }
            }
            WFENCE();
            // -- co = h2@Wf + bf  (32 outputs; lanes 32-63 duplicate) --
            {
                const int r = tid & 31;
                float a = sm[O_Bf + r];
                #pragma unroll
                for (int g = 0; g < 8; ++g) {
                    float4 hv = *(const float4*)&sm[O_H2 + g*4];
                    a += dot4(hv, ldsw(sm + O_WfT, r, g, 32));
                }
                if (tid < 32) sm[O_Co + tid] = a;
            }
            WFENCE();
            // -- d1 = relu(co[:31]@Wd1 + bd1)  (col 31 zero-weighted) --
            {
                float a = sm[O_Bd1 + tid];
                #pragma unroll
                for (int g = 0; g < 8; ++g) {
                    float4 cv = *(const float4*)&sm[O_Co + g*4];
                    a += dot4(cv, ldsw(sm + O_Wd1T, tid, g, 32));
                }
                sm[O_D1 + tid] = fmaxf(a, 0.0f);
            }
            WFENCE();
            // -- logits + softmax(64) + gate update --
            {
                float a = sm[O_Bd2 + tid];
                #pragma unroll
                for (int g = 0; g < 16; ++g) {
                    float4 dv = *(const float4*)&sm[O_D1 + g*4];
                    a += dot4(dv, ldsw(sm + O_Wd2T, tid, g, 64));
                }
                float mx = a;
                #pragma unroll
                for (int o = 32; o >= 1; o >>= 1) mx = fmaxf(mx, __shfl_xor(mx, o));
                float ex = __expf(a - mx);
                float ssum = ex;
                #pragma unroll
                for (int o = 32; o >= 1; o >>= 1) ssum += __shfl_xor(ssum, o);
                float g = ex / ssum;
                float th = sigf(sm[O_Co + 31]);
                gate_reg = g * th + gate_reg * (1.0f - th);
                sm[O_Gate + tid] = gate_reg;
            }
        }

        __syncthreads();   // B: nsT (+gate) ready

        if (tid < 64) {
            // ======== P8: state = gate @ ns ; pred ; err ========
            const int row = tid & 31;
            float acc = 0.0f;
            #pragma unroll
            for (int g = 0; g < 16; ++g) {
                float4 gv = *(const float4*)&sm[O_Gate + g*4];
                float2 n0 = *(const float2*)&sm[O_NsT + row*66 + g*4];
                float2 n1 = *(const float2*)&sm[O_NsT + row*66 + g*4 + 2];
                acc += gv.x*n0.x + gv.y*n0.y + gv.z*n1.x + gv.w*n1.y;
            }
            if (tid < 32) {
                sm[O_State + tid] = acc;
                if (tid == 31) {
                    float p = fminf(fmaxf(acc, 0.0f), 1.0f);
                    sm[O_Pred + t] = p;
                    sm[O_Err] = p - sm[O_Y + t];
                }
            }
        }
    }

    // ---------------- epilogue: flush preds ----------------
    __syncthreads();
    for (int i = tid; i < Lsz; i += NT) out[b*Lsz + i] = sm[O_Pred + i];
}

extern "C" void kernel_launch(void* const* d_in, const int* in_sizes, int n_in,
                              void* d_out, int out_size, void* d_ws, size_t ws_size,
                              hipStream_t stream) {
    const float* x    = (const float*)d_in[0];
    const float* y    = (const float*)d_in[1];
    const float* s0   = (const float*)d_in[2];
    const float* err0 = (const float*)d_in[3];
    const float* g0   = (const float*)d_in[4];
    const float* Wc   = (const float*)d_in[5];
    const float* Ux   = (const float*)d_in[6];
    const float* bc   = (const float*)d_in[7];
    const float* mu   = (const float*)d_in[8];
    const float* Wx1  = (const float*)d_in[9];
    const float* Wh1  = (const float*)d_in[10];
    const float* b1   = (const float*)d_in[11];
    const float* Wx2  = (const float*)d_in[12];
    const float* Wh2  = (const float*)d_in[13];
    const float* b2   = (const float*)d_in[14];
    const float* Wo   = (const float*)d_in[15];
    const float* bo   = (const float*)d_in[16];
    const float* Wlin = (const float*)d_in[17];
    const float* blin = (const float*)d_in[18];
    const float* Wd1  = (const float*)d_in[19];
    const float* bd1  = (const float*)d_in[20];
    const float* Wd2  = (const float*)d_in[21];
    const float* bd2  = (const float*)d_in[22];
    float* out = (float*)d_out;

    static bool attr_set = false;
    if (!attr_set) {
        hipFuncSetAttribute((const void*)dnc_kernel,
                            hipFuncAttributeMaxDynamicSharedMemorySize,
                            SMEM_FLOATS * sizeof(float));
        attr_set = true;
    }

    hipLaunchKernelGGL(dnc_kernel, dim3(Bsz), dim3(NT),
                       SMEM_FLOATS * sizeof(float), stream,
                       x, y, s0, err0, g0, Wc, Ux, bc, mu,
                       Wx1, Wh1, b1, Wx2, Wh2, b2,
                       Wo, bo, Wlin, blin, Wd1, bd1, Wd2, bd2, out);
}